// Round 5
// baseline (76.974 us; speedup 1.0000x reference)
//
#include <hip/hip_runtime.h>

#define B_   4096
#define C_   64
#define F_   128
#define XLD  132   // padded x row stride (floats)
#define ROWS 16    // batches per block
#define GR   8     // batches per group (2 groups)

typedef __attribute__((address_space(3))) unsigned int lds_u32;
typedef __attribute__((address_space(1))) unsigned int glb_u32;

// Stage 64KB of W into LDS by ONE wave (64 lanes): 64 x global_load_lds width-16.
// Dest is wave-uniform base + lane*16 (HW requirement).
__device__ __forceinline__ void stage_w_wave(const float* __restrict__ Wg,
                                             float* buf, int ln) {
    #pragma unroll
    for (int i = 0; i < 64; ++i) {
        const int off = i * 256 + ln * 4;   // floats; 1KB per instruction
        __builtin_amdgcn_global_load_lds((const glb_u32*)(Wg + off),
                                         (lds_u32*)(buf + off), 16, 0, 0);
    }
}

// One group's 4-layer MLP by ONE wave. rg = lane>>5 (rows 4rg..4rg+3),
// cq = lane&31 (cols 4cq..4cq+3). Per k4: 4 broadcast x-reads + 4 2-way W-reads
// feed 64 FMAs. W double-buffered: stage stages[l] -> wb[(l+1)&1] during layer l,
// drained by the vmcnt(0) after the k-loop. No barriers (single-wave privacy).
__device__ __forceinline__ void mlp_group(float* __restrict__ xg,
                                          float* __restrict__ wb0,
                                          float* __restrict__ wb1,
                                          const float* __restrict__ st0,
                                          const float* __restrict__ st1,
                                          const float* __restrict__ st2,
                                          const float* __restrict__ st3,
                                          const float4* __restrict__ bias,
                                          float* __restrict__ outp,
                                          int rg, int cq, int ln) {
    float* wbufs[2] = {wb0, wb1};
    const float* stages[4] = {st0, st1, st2, st3};

    #pragma unroll
    for (int l = 0; l < 4; ++l) {
        if (stages[l]) stage_w_wave(stages[l], wbufs[(l + 1) & 1], ln);
        const float* wl = wbufs[l & 1];
        const float* xr = xg + (4 * rg) * XLD;
        const float* wc = wl + cq * 4;

        float4 a0 = {0,0,0,0}, a1 = {0,0,0,0}, a2 = {0,0,0,0}, a3 = {0,0,0,0};
        #pragma unroll 8
        for (int k4 = 0; k4 < 32; ++k4) {
            float4 x0 = *(const float4*)(xr + 0 * XLD + k4 * 4);
            float4 x1 = *(const float4*)(xr + 1 * XLD + k4 * 4);
            float4 x2 = *(const float4*)(xr + 2 * XLD + k4 * 4);
            float4 x3 = *(const float4*)(xr + 3 * XLD + k4 * 4);
            #pragma unroll
            for (int i = 0; i < 4; ++i) {
                const float4 w = *(const float4*)(wc + (k4 * 4 + i) * F_);
                const float s0 = (&x0.x)[i], s1 = (&x1.x)[i];
                const float s2 = (&x2.x)[i], s3 = (&x3.x)[i];
                a0.x += s0 * w.x; a0.y += s0 * w.y; a0.z += s0 * w.z; a0.w += s0 * w.w;
                a1.x += s1 * w.x; a1.y += s1 * w.y; a1.z += s1 * w.z; a1.w += s1 * w.w;
                a2.x += s2 * w.x; a2.y += s2 * w.y; a2.z += s2 * w.z; a2.w += s2 * w.w;
                a3.x += s3 * w.x; a3.y += s3 * w.y; a3.z += s3 * w.z; a3.w += s3 * w.w;
            }
        }
        asm volatile("s_waitcnt vmcnt(0)" ::: "memory");  // next-layer W staged

        const float4 b4 = bias[l];
        float4 r[4] = {a0, a1, a2, a3};
        if (l < 3) {
            #pragma unroll
            for (int j = 0; j < 4; ++j) {
                float4 v;
                v.x = fmaxf(r[j].x + b4.x, 0.f); v.y = fmaxf(r[j].y + b4.y, 0.f);
                v.z = fmaxf(r[j].z + b4.z, 0.f); v.w = fmaxf(r[j].w + b4.w, 0.f);
                *(float4*)(xg + (4 * rg + j) * XLD + cq * 4) = v;
            }
        } else {
            #pragma unroll
            for (int j = 0; j < 4; ++j) {
                float4 v;
                v.x = r[j].x + b4.x; v.y = r[j].y + b4.y;
                v.z = r[j].z + b4.z; v.w = r[j].w + b4.w;
                ((float4*)(outp + (4 * rg + j) * F_))[cq] = v;
            }
        }
    }
}

// Streamer: thread owns (local batch bl, float4-col f4); sums 64 channels in
// two independent chains (2x in-flight), writes the mean into xb[g].
__device__ __forceinline__ void stream_group(const float* __restrict__ emb,
                                             float* __restrict__ xg,
                                             int row0, int g, int bl, int f4) {
    const float4* src = (const float4*)(emb + (size_t)(row0 + g * GR + bl) * (C_ * F_)) + f4;
    float4 aA = {0,0,0,0}, aB = {0,0,0,0};
    #pragma unroll 8
    for (int c = 0; c < 32; ++c) {
        const float4 v0 = src[c * 32];          // channel c
        const float4 v1 = src[(c + 32) * 32];   // channel c+32
        aA.x += v0.x; aA.y += v0.y; aA.z += v0.z; aA.w += v0.w;
        aB.x += v1.x; aB.y += v1.y; aB.z += v1.z; aB.w += v1.w;
    }
    const float inv = 1.0f / (float)C_;
    float4 s;
    s.x = (aA.x + aB.x) * inv; s.y = (aA.y + aB.y) * inv;
    s.z = (aA.z + aB.z) * inv; s.w = (aA.w + aB.w) * inv;
    *(float4*)(xg + bl * XLD + f4 * 4) = s;
}

// ---------------------------------------------------------------------------
// 256 blocks x 320 threads. Waves 0-3 stream means; wave 4 runs the MLP.
//   stream G0 -> B1 -> [stream G1 || MLP G0] -> B2 -> MLP G1
// ---------------------------------------------------------------------------
__global__ __launch_bounds__(320, 1) void fused_kernel(const float* __restrict__ emb,
                                                       const float* __restrict__ W0,
                                                       const float* __restrict__ b0,
                                                       const float* __restrict__ W1,
                                                       const float* __restrict__ b1,
                                                       const float* __restrict__ W2,
                                                       const float* __restrict__ b2,
                                                       const float* __restrict__ Wr,
                                                       const float* __restrict__ br,
                                                       float* __restrict__ out) {
    __shared__ float Wbuf[2][F_ * F_];    // 128 KB
    __shared__ float xb[2][GR * XLD];     // 8.25 KB  (total ~136.3 KB, 1 block/CU)

    const int t    = threadIdx.x;
    const int row0 = blockIdx.x * ROWS;

    const int bl = t >> 5;         // streamer: local batch 0..7
    const int f4 = t & 31;         // streamer: float4 col
    const int ln = t - 256;        // mlp wave lane 0..63
    const int rg = ln >> 5;        // row group
    const int cq = ln & 31;        // col quad

    float4 bias[4];

    // ---- phase 0: stream G0  ||  (mlp wave: preload biases + stage W0) ----
    if (t < 256) {
        stream_group(emb, xb[0], row0, 0, bl, f4);
    } else {
        bias[0] = ((const float4*)b0)[cq];
        bias[1] = ((const float4*)b1)[cq];
        bias[2] = ((const float4*)b2)[cq];
        bias[3] = ((const float4*)br)[cq];
        stage_w_wave(W0, Wbuf[0], ln);
    }
    __syncthreads();   // B1: xb[0] visible; wave4's W0 stage + biases drained

    // ---- phase 1: stream G1  ||  MLP G0 (stages W1,W2,W3, then W0 for G1) --
    if (t < 256) {
        stream_group(emb, xb[1], row0, 1, bl, f4);
    } else {
        mlp_group(xb[0], Wbuf[0], Wbuf[1], W1, W2, Wr, W0, bias,
                  out + (size_t)row0 * F_, rg, cq, ln);
    }
    __syncthreads();   // B2: xb[1] visible; W0 re-stage drained

    // ---- phase 2: MLP G1 (streamers exit) ---------------------------------
    if (t >= 256) {
        mlp_group(xb[1], Wbuf[0], Wbuf[1], W1, W2, Wr, nullptr, bias,
                  out + (size_t)(row0 + GR) * F_, rg, cq, ln);
    }
}

extern "C" void kernel_launch(void* const* d_in, const int* in_sizes, int n_in,
                              void* d_out, int out_size, void* d_ws, size_t ws_size,
                              hipStream_t stream) {
    const float* emb = (const float*)d_in[0];
    const float* W0  = (const float*)d_in[1];
    const float* b0  = (const float*)d_in[2];
    const float* W1  = (const float*)d_in[3];
    const float* b1  = (const float*)d_in[4];
    const float* W2  = (const float*)d_in[5];
    const float* b2  = (const float*)d_in[6];
    const float* Wr  = (const float*)d_in[7];
    const float* br  = (const float*)d_in[8];

    fused_kernel<<<B_ / ROWS, 320, 0, stream>>>(emb, W0, b0, W1, b1, W2, b2,
                                                Wr, br, (float*)d_out);
}

// Round 6
// 45.081 us; speedup vs baseline: 1.7075x; 1.7075x over previous
//
#include <hip/hip_runtime.h>

#define B_   4096
#define C_   64
#define F_   128
#define XLD  132   // padded x row stride (floats)
#define ROWS 16    // batches per MLP block

typedef __attribute__((address_space(3))) unsigned int lds_u32;
typedef __attribute__((address_space(1))) unsigned int glb_u32;

// ---------------------------------------------------------------------------
// Kernel A (R1 verbatim): e_bar[b][f] = (1/C) * sum_c emb[b][c][f]
// 4096 blocks x 256 threads -> ~32 waves/CU, BW-saturating. ~21us.
// ---------------------------------------------------------------------------
__global__ __launch_bounds__(256) void mean_kernel(const float* __restrict__ emb,
                                                   float* __restrict__ ebar) {
    const int b = blockIdx.x;
    const int t = threadIdx.x;
    const int fc = t & 31;
    const int cr = t >> 5;

    const float4* src = (const float4*)(emb + (size_t)b * C_ * F_);
    float4 s = make_float4(0.f, 0.f, 0.f, 0.f);
    #pragma unroll
    for (int c = 0; c < C_ / 8; ++c) {
        float4 v = src[(cr + c * 8) * (F_ / 4) + fc];
        s.x += v.x; s.y += v.y; s.z += v.z; s.w += v.w;
    }

    __shared__ float4 part[8][32];
    part[cr][fc] = s;
    __syncthreads();
    if (t < 32) {
        float4 acc = part[0][t];
        #pragma unroll
        for (int i = 1; i < 8; ++i) {
            float4 v = part[i][t];
            acc.x += v.x; acc.y += v.y; acc.z += v.z; acc.w += v.w;
        }
        const float inv = 1.0f / (float)C_;
        acc.x *= inv; acc.y *= inv; acc.z *= inv; acc.w *= inv;
        ((float4*)(ebar + (size_t)b * F_))[t] = acc;
    }
}

// Async 64KB W stage global->LDS (width 16, lane-linear dest). 256 thr x 16.
__device__ __forceinline__ void stage_w(const float* __restrict__ Wg,
                                        float* buf, int t) {
    #pragma unroll
    for (int i = 0; i < 16; ++i) {
        const int off = i * 1024 + t * 4;   // float idx; bytes = i*4096 + t*16
        __builtin_amdgcn_global_load_lds((const glb_u32*)(Wg + off),
                                         (lds_u32*)(buf + off), 16, 0, 0);
    }
}

// ---------------------------------------------------------------------------
// Kernel B: fused 4-layer MLP. 256 blocks x 256 threads, 16 rows/block,
// 1 block/CU (LDS 136.5KB).
// Wave w owns rows 4w..4w+3 (wave-private across ALL layers -> no x barriers).
// Within a wave: kh = lane>=32 takes k-half [64,128); pair (l, l^32) owns
// 4 rows x 1 colquad (q = lane&31). Per k4: 4 broadcast x-reads + 4 W-reads
// (2 rows 64 apart -> same banks, 2-way = free) feed 64 FMA-inst.
// k-halves reduced via __shfl_xor(32). W double-buffered, staged async;
// the one __syncthreads per layer drains vmcnt.
// ---------------------------------------------------------------------------
__global__ __launch_bounds__(256, 1) void mlp_kernel(const float* __restrict__ xin,
                                                     const float* __restrict__ W0,
                                                     const float* __restrict__ b0,
                                                     const float* __restrict__ W1,
                                                     const float* __restrict__ b1,
                                                     const float* __restrict__ W2,
                                                     const float* __restrict__ b2,
                                                     const float* __restrict__ Wr,
                                                     const float* __restrict__ br,
                                                     float* __restrict__ out) {
    __shared__ float Wbuf[2][F_ * F_];   // 128 KB
    __shared__ float xb[ROWS * XLD];     // 8.25 KB

    const int t    = threadIdx.x;
    const int w    = t >> 6;     // wave -> rows 4w..4w+3
    const int l    = t & 63;
    const int kh   = l >> 5;     // k-half 0/1
    const int q    = l & 31;     // owned colquad
    const int row0 = blockIdx.x * ROWS;

    stage_w(W0, Wbuf[0], t);

    // x load: wave-private rows, 128 float4 per wave, 2 per lane, coalesced.
    {
        const float4* src = (const float4*)(xin + (size_t)(row0 + 4 * w) * F_);
        #pragma unroll
        for (int i = 0; i < 2; ++i) {
            const int s = l + i * 64;
            const int r = s >> 5, c = s & 31;
            *(float4*)(xb + (4 * w + r) * XLD + c * 4) = src[s];
        }
    }

    float4 bias[4];
    bias[0] = ((const float4*)b0)[q];
    bias[1] = ((const float4*)b1)[q];
    bias[2] = ((const float4*)b2)[q];
    bias[3] = ((const float4*)br)[q];

    __syncthreads();   // W0 staged (vmcnt drained at barrier)

    const float* stages[3] = {W1, W2, Wr};

    #pragma unroll
    for (int layer = 0; layer < 4; ++layer) {
        if (layer < 3) stage_w(stages[layer], Wbuf[(layer + 1) & 1], t);
        const float* Wl    = Wbuf[layer & 1];
        const float* xrow  = xb + (4 * w) * XLD + kh * 64;  // k-half col offset
        const float* wbase = Wl + (kh * 64) * F_ + q * 4;

        float acc[4][4];
        #pragma unroll
        for (int j = 0; j < 4; ++j)
            #pragma unroll
            for (int jj = 0; jj < 4; ++jj) acc[j][jj] = 0.f;

        #pragma unroll 8
        for (int k4 = 0; k4 < 16; ++k4) {
            float4 xv[4];
            #pragma unroll
            for (int j = 0; j < 4; ++j)
                xv[j] = *(const float4*)(xrow + j * XLD + k4 * 4);
            #pragma unroll
            for (int i = 0; i < 4; ++i) {
                const float4 wv = *(const float4*)(wbase + (k4 * 4 + i) * F_);
                #pragma unroll
                for (int j = 0; j < 4; ++j) {
                    const float xs = (&xv[j].x)[i];   // static after unroll
                    acc[j][0] += xs * wv.x; acc[j][1] += xs * wv.y;
                    acc[j][2] += xs * wv.z; acc[j][3] += xs * wv.w;
                }
            }
        }

        // cross-k-half reduce in registers
        #pragma unroll
        for (int j = 0; j < 4; ++j)
            #pragma unroll
            for (int jj = 0; jj < 4; ++jj)
                acc[j][jj] += __shfl_xor(acc[j][jj], 32, 64);

        const float4 b4 = bias[layer];
        if (layer < 3) {
            // kh=0 lanes write rows 0,1; kh=1 lanes write rows 2,3
            #pragma unroll
            for (int jj = 0; jj < 2; ++jj) {
                const int j = kh * 2 + jj;
                float4 v;
                v.x = fmaxf(acc[j][0] + b4.x, 0.f);
                v.y = fmaxf(acc[j][1] + b4.y, 0.f);
                v.z = fmaxf(acc[j][2] + b4.z, 0.f);
                v.w = fmaxf(acc[j][3] + b4.w, 0.f);
                *(float4*)(xb + (4 * w + j) * XLD + q * 4) = v;
            }
            __syncthreads();   // W[layer+1] staged; xb writes ordered (same wave)
        } else {
            float4* o = (float4*)(out + (size_t)(row0 + 4 * w) * F_);
            #pragma unroll
            for (int jj = 0; jj < 2; ++jj) {
                const int j = kh * 2 + jj;
                float4 v;
                v.x = acc[j][0] + b4.x; v.y = acc[j][1] + b4.y;
                v.z = acc[j][2] + b4.z; v.w = acc[j][3] + b4.w;
                o[j * 32 + q] = v;
            }
        }
    }
}

extern "C" void kernel_launch(void* const* d_in, const int* in_sizes, int n_in,
                              void* d_out, int out_size, void* d_ws, size_t ws_size,
                              hipStream_t stream) {
    const float* emb = (const float*)d_in[0];
    const float* W0  = (const float*)d_in[1];
    const float* b0  = (const float*)d_in[2];
    const float* W1  = (const float*)d_in[3];
    const float* b1  = (const float*)d_in[4];
    const float* W2  = (const float*)d_in[5];
    const float* b2  = (const float*)d_in[6];
    const float* Wr  = (const float*)d_in[7];
    const float* br  = (const float*)d_in[8];

    float* ebar = (float*)d_ws;  // 2 MB scratch

    mean_kernel<<<B_, 256, 0, stream>>>(emb, ebar);
    mlp_kernel<<<B_ / ROWS, 256, 0, stream>>>(ebar, W0, b0, W1, b1, W2, b2,
                                              Wr, br, (float*)d_out);
}

// Round 7
// 32.429 us; speedup vs baseline: 2.3736x; 1.3901x over previous
//
#include <hip/hip_runtime.h>

#define B_ 4096
#define C_ 64
#define F_ 128
#define KP 136                       // padded K stride (bf16 elems): 272B rows -> 2-way banks
#define PLANE_E (F_ * KP)            // 17408 u16 elems per plane
#define LAYER_E (2 * PLANE_E)        // hi+lo planes, 34816 elems = 69632 B

typedef __attribute__((address_space(3))) unsigned int lds_u32;
typedef __attribute__((address_space(1))) unsigned int glb_u32;
typedef __attribute__((ext_vector_type(8))) short short8;   // 8 bf16 (4 VGPRs)
typedef __attribute__((ext_vector_type(4))) float f32x4;

__device__ __forceinline__ unsigned short bf16_trunc(float f) {
    union { float f; unsigned u; } v; v.f = f;
    return (unsigned short)(v.u >> 16);
}
__device__ __forceinline__ float bf16_tof(unsigned short h) {
    union { unsigned u; float f; } v; v.u = ((unsigned)h) << 16;
    return v.f;
}

// ---------------------------------------------------------------------------
// Kernel A: per-batch mean (R1-proven stream) + W-prep folded into blocks 0-31.
// Prep: block p<32: layer=p>>3, stripe s=p&7 -> writes Wt[layer] rows n in
// [16s,16s+16) as bf16 hi/lo planes, K-innermost, K-padded to 136.
// ---------------------------------------------------------------------------
__global__ __launch_bounds__(256) void mean_prep_kernel(const float* __restrict__ emb,
                                                        float* __restrict__ ebar,
                                                        const float* __restrict__ W0,
                                                        const float* __restrict__ W1,
                                                        const float* __restrict__ W2,
                                                        const float* __restrict__ Wr,
                                                        unsigned short* __restrict__ wprep) {
    __shared__ float4 part[8][32];
    __shared__ float  tile[128 * 17];   // prep transpose tile [k][n'] pad 17

    const int b = blockIdx.x;
    const int t = threadIdx.x;
    const int fc = t & 31;
    const int cr = t >> 5;

    // ---- stream: mean over C=64 channels of batch b ----
    {
        const float4* src = (const float4*)(emb + (size_t)b * C_ * F_);
        float4 s = make_float4(0.f, 0.f, 0.f, 0.f);
        #pragma unroll
        for (int c = 0; c < C_ / 8; ++c) {
            float4 v = src[(cr + c * 8) * (F_ / 4) + fc];
            s.x += v.x; s.y += v.y; s.z += v.z; s.w += v.w;
        }
        part[cr][fc] = s;
        __syncthreads();
        if (t < 32) {
            float4 acc = part[0][t];
            #pragma unroll
            for (int i = 1; i < 8; ++i) {
                float4 v = part[i][t];
                acc.x += v.x; acc.y += v.y; acc.z += v.z; acc.w += v.w;
            }
            const float inv = 1.0f / (float)C_;
            acc.x *= inv; acc.y *= inv; acc.z *= inv; acc.w *= inv;
            ((float4*)(ebar + (size_t)b * F_))[t] = acc;
        }
    }

    // ---- prep (32 blocks, hidden under the 4096-block stream) ----
    if (b < 32) {
        const int layer = b >> 3;
        const int s     = b & 7;
        const float* W = layer == 0 ? W0 : layer == 1 ? W1 : layer == 2 ? W2 : Wr;

        // load W[k][16s..16s+16) for all k: thread t -> k=t&127, half=t>>7
        {
            const int kk = t & 127, half = t >> 7;
            const float4* wr_ = (const float4*)(W + (size_t)kk * F_ + 16 * s + 8 * half);
            const float4 v0 = wr_[0], v1 = wr_[1];
            float* dst = tile + kk * 17 + 8 * half;
            dst[0] = v0.x; dst[1] = v0.y; dst[2] = v0.z; dst[3] = v0.w;
            dst[4] = v1.x; dst[5] = v1.y; dst[6] = v1.z; dst[7] = v1.w;
        }
        __syncthreads();
        // transpose-out: thread t -> n'=t&15, kq=t>>4 owns k in [8kq, 8kq+8)
        {
            const int np = t & 15, kq = t >> 4;
            unsigned int hw[4], lw[4];
            #pragma unroll
            for (int p = 0; p < 4; ++p) {
                const float f0 = tile[(kq * 8 + 2 * p)     * 17 + np];
                const float f1 = tile[(kq * 8 + 2 * p + 1) * 17 + np];
                const unsigned short h0 = bf16_trunc(f0), h1 = bf16_trunc(f1);
                const unsigned short l0 = bf16_trunc(f0 - bf16_tof(h0));
                const unsigned short l1 = bf16_trunc(f1 - bf16_tof(h1));
                hw[p] = (unsigned)h0 | ((unsigned)h1 << 16);
                lw[p] = (unsigned)l0 | ((unsigned)l1 << 16);
            }
            const size_t base = (size_t)layer * LAYER_E + (size_t)(16 * s + np) * KP + kq * 8;
            *(int4*)(wprep + base)          = make_int4(hw[0], hw[1], hw[2], hw[3]);
            *(int4*)(wprep + base + PLANE_E) = make_int4(lw[0], lw[1], lw[2], lw[3]);
        }
    }
}

// Async stage of one layer's Wt block (69632 B) into LDS: 17 x (256 thr x 16B).
// Linear dest = linear source layout (prep wrote the padded layout directly).
__device__ __forceinline__ void stage_w(const unsigned short* __restrict__ src,
                                        unsigned short* dst, int t) {
    #pragma unroll
    for (int i = 0; i < 17; ++i) {
        const int e = i * 2048 + t * 8;   // u16 elems; bytes = i*4096 + t*16
        __builtin_amdgcn_global_load_lds((const glb_u32*)(src + e),
                                         (lds_u32*)(dst + e), 16, 0, 0);
    }
}

// ---------------------------------------------------------------------------
// Kernel B: MFMA MLP. 256 blocks x 256 thr (4 waves), 16 rows/block.
// Split-bf16: x = xh+xl, W = Wh+Wl; acc += xh@Wh + xl@Wh + xh@Wl (fp32 MFMA acc).
// Wave w owns col-tiles {2w, 2w+1}. mfma_f32_16x16x32_bf16:
//   A: row=lane&15, k=(lane>>4)*8+e   (x stored [row][k], k-contiguous)
//   B: col=lane&15, k=(lane>>4)*8+e   (Wt stored [n][k], k-contiguous)
//   C: col=lane&15, row=(lane>>4)*4+reg
// W double-buffered (async global_load_lds), x double-buffered, 1 barrier/layer.
// ---------------------------------------------------------------------------
__global__ __launch_bounds__(256, 1) void mlp_mfma_kernel(const float* __restrict__ ebar,
                                                          const unsigned short* __restrict__ wprep,
                                                          const float* __restrict__ b0,
                                                          const float* __restrict__ b1,
                                                          const float* __restrict__ b2,
                                                          const float* __restrict__ br,
                                                          float* __restrict__ out) {
    __shared__ unsigned short wb[2][LAYER_E];      // 139264 B
    __shared__ unsigned short xbuf[2][2][16 * KP]; // 17408 B (buf, plane=hi/lo)

    const int t = threadIdx.x;
    const int w = t >> 6;          // wave -> col-tiles 2w, 2w+1
    const int l = t & 63;
    const int q = l >> 4;          // k-group / row-quad
    const int c = l & 15;          // A-row (batch) & B/C-col
    const int row0 = blockIdx.x * 16;

    stage_w(wprep, wb[0], t);      // W0

    // x prologue: 16 rows x 128 f32 -> bf16 hi/lo planes of xbuf[0]
    {
        const float4* src = (const float4*)(ebar + (size_t)row0 * F_);
        #pragma unroll
        for (int i = 0; i < 2; ++i) {
            const int idx = t + i * 256;        // float4 slot 0..511
            const int r = idx >> 5, c4 = idx & 31;
            const float4 v = src[idx];
            ushort4 h, lo;
            h.x = bf16_trunc(v.x); lo.x = bf16_trunc(v.x - bf16_tof(h.x));
            h.y = bf16_trunc(v.y); lo.y = bf16_trunc(v.y - bf16_tof(h.y));
            h.z = bf16_trunc(v.z); lo.z = bf16_trunc(v.z - bf16_tof(h.z));
            h.w = bf16_trunc(v.w); lo.w = bf16_trunc(v.w - bf16_tof(h.w));
            *(ushort4*)(&xbuf[0][0][r * KP + c4 * 4]) = h;
            *(ushort4*)(&xbuf[0][1][r * KP + c4 * 4]) = lo;
        }
    }

    // biases for my two output tiles
    float bias[4][2];
    #pragma unroll
    for (int i = 0; i < 2; ++i) {
        const int col = (2 * w + i) * 16 + c;
        bias[0][i] = b0[col]; bias[1][i] = b1[col];
        bias[2][i] = b2[col]; bias[3][i] = br[col];
    }

    __syncthreads();   // x visible, W0 staged (barrier drains vmcnt)

    #pragma unroll
    for (int L = 0; L < 4; ++L) {
        if (L < 3) stage_w(wprep + (size_t)(L + 1) * LAYER_E, wb[(L + 1) & 1], t);
        const unsigned short* xh = xbuf[L & 1][0];
        const unsigned short* xl = xbuf[L & 1][1];
        const unsigned short* wl = wb[L & 1];

        short8 ah[4], al[4];
        #pragma unroll
        for (int kk = 0; kk < 4; ++kk) {
            const int xo = c * KP + kk * 32 + q * 8;
            ah[kk] = *(const short8*)(xh + xo);
            al[kk] = *(const short8*)(xl + xo);
        }

        f32x4 acc[2] = {{0.f, 0.f, 0.f, 0.f}, {0.f, 0.f, 0.f, 0.f}};
        #pragma unroll
        for (int i = 0; i < 2; ++i) {
            const int n = (2 * w + i) * 16 + c;
            #pragma unroll
            for (int kk = 0; kk < 4; ++kk) {
                const int ko = kk * 32 + q * 8;
                const short8 bh = *(const short8*)(wl + n * KP + ko);
                const short8 bl = *(const short8*)(wl + PLANE_E + n * KP + ko);
                acc[i] = __builtin_amdgcn_mfma_f32_16x16x32_bf16(ah[kk], bh, acc[i], 0, 0, 0);
                acc[i] = __builtin_amdgcn_mfma_f32_16x16x32_bf16(al[kk], bh, acc[i], 0, 0, 0);
                acc[i] = __builtin_amdgcn_mfma_f32_16x16x32_bf16(ah[kk], bl, acc[i], 0, 0, 0);
            }
        }

        if (L < 3) {
            unsigned short* xnh = xbuf[(L + 1) & 1][0];
            unsigned short* xnl = xbuf[(L + 1) & 1][1];
            #pragma unroll
            for (int i = 0; i < 2; ++i) {
                #pragma unroll
                for (int j = 0; j < 4; ++j) {
                    float v = acc[i][j] + bias[L][i];
                    v = fmaxf(v, 0.f);
                    const int row = q * 4 + j;
                    const int col = (2 * w + i) * 16 + c;
                    const unsigned short h = bf16_trunc(v);
                    xnh[row * KP + col] = h;
                    xnl[row * KP + col] = bf16_trunc(v - bf16_tof(h));
                }
            }
            __syncthreads();   // x' visible; next W staged (vmcnt drained)
        } else {
            #pragma unroll
            for (int i = 0; i < 2; ++i) {
                #pragma unroll
                for (int j = 0; j < 4; ++j) {
                    out[(size_t)(row0 + q * 4 + j) * F_ + (2 * w + i) * 16 + c]
                        = acc[i][j] + bias[3][i];
                }
            }
        }
    }
}

extern "C" void kernel_launch(void* const* d_in, const int* in_sizes, int n_in,
                              void* d_out, int out_size, void* d_ws, size_t ws_size,
                              hipStream_t stream) {
    const float* emb = (const float*)d_in[0];
    const float* W0  = (const float*)d_in[1];
    const float* b0  = (const float*)d_in[2];
    const float* W1  = (const float*)d_in[3];
    const float* b1  = (const float*)d_in[4];
    const float* W2  = (const float*)d_in[5];
    const float* b2  = (const float*)d_in[6];
    const float* Wr  = (const float*)d_in[7];
    const float* br  = (const float*)d_in[8];

    float*          ebar  = (float*)d_ws;                          // 2 MB
    unsigned short* wprep = (unsigned short*)((char*)d_ws + 2097152); // 272 KB

    mean_prep_kernel<<<B_, 256, 0, stream>>>(emb, ebar, W0, W1, W2, Wr, wprep);
    mlp_mfma_kernel<<<B_ / 16, 256, 0, stream>>>(ebar, wprep, b0, b1, b2, br,
                                                 (float*)d_out);
}